// Round 1
// baseline (204.055 us; speedup 1.0000x reference)
//
#include <hip/hip_runtime.h>

#define LOG2E 1.44269504088896340736f
#define LN2   0.69314718055994530942f
#define S_    8192
#define TPB   256
#define KPT   32   // timesteps per thread: 256*32 = 8192

#if __has_builtin(__builtin_amdgcn_exp2f)
__device__ __forceinline__ float exp2f_(float x){ return __builtin_amdgcn_exp2f(x); }
#else
__device__ __forceinline__ float exp2f_(float x){ return __expf(x * LN2); }
#endif
#if __has_builtin(__builtin_amdgcn_logf)
__device__ __forceinline__ float log2f_(float x){ return __builtin_amdgcn_logf(x); }
#else
__device__ __forceinline__ float log2f_(float x){ return __logf(x) * LOG2E; }
#endif

// log-sum-exp of 3 values in log2 domain
__device__ __forceinline__ float lse3_2(float a, float b, float c){
    float m = fmaxf(fmaxf(a,b),c);
    return m + log2f_(exp2f_(a-m) + exp2f_(b-m) + exp2f_(c-m));
}

// renorm row (a,b,c): scale max into [1,2) by an exact power of two; s += log2(scale removed)
__device__ __forceinline__ void renorm3(float&a, float&b, float&c, float&s){
    float m = fmaxf(fmaxf(a,b),c);
    int e = (__float_as_int(m) >> 23) & 0xff;      // biased exponent of max
    float rs = __int_as_float((254 - e) << 23);    // 2^(127-e), exact
    a *= rs; b *= rs; c *= rs;
    s += (float)(e - 127);
}

// (A,As) <- (A,As) ∘ (Bv,Bs): semiring product; rows = linear mantissa + log2 row-scale
__device__ __forceinline__ void combine9(float* A, float* As, const float* Bv, const float* Bs){
    float mb = fmaxf(fmaxf(Bs[0],Bs[1]),Bs[2]);
    float f0 = exp2f_(Bs[0]-mb), f1 = exp2f_(Bs[1]-mb), f2 = exp2f_(Bs[2]-mb);
    float b00=Bv[0]*f0, b01=Bv[1]*f0, b02=Bv[2]*f0;
    float b10=Bv[3]*f1, b11=Bv[4]*f1, b12=Bv[5]*f1;
    float b20=Bv[6]*f2, b21=Bv[7]*f2, b22=Bv[8]*f2;
#pragma unroll
    for (int i=0;i<3;i++){
        float a0=A[i*3+0], a1=A[i*3+1], a2=A[i*3+2];
        float c0 = a0*b00 + a1*b10 + a2*b20;
        float c1 = a0*b01 + a1*b11 + a2*b21;
        float c2 = a0*b02 + a1*b12 + a2*b22;
        float s  = As[i] + mb;
        renorm3(c0,c1,c2,s);
        A[i*3+0]=c0; A[i*3+1]=c1; A[i*3+2]=c2; As[i]=s;
    }
}

extern "C" __global__ __launch_bounds__(TPB)
void crf_fwd(const float* __restrict__ em, const int* __restrict__ lab,
             const float* __restrict__ stt, const float* __restrict__ trt,
             const float* __restrict__ ent, float* __restrict__ ws)
{
    const int b   = blockIdx.x;
    const int tid = threadIdx.x;
    const int ln  = tid & 63;
    const int wv  = tid >> 6;

    __shared__ float tLds[9], sLds[3], eLds[3];
    __shared__ float wV[4][9];
    __shared__ float wS2[4][3];
    __shared__ float wSc[4];
    if (tid < 9) tLds[tid] = trt[tid];
    if (tid < 3) { sLds[tid] = stt[tid]; eLds[tid] = ent[tid]; }
    __syncthreads();

    // W[k][j] = exp(T[k][j]) — linear-domain transition weights
    float W00=__expf(trt[0]), W01=__expf(trt[1]), W02=__expf(trt[2]);
    float W10=__expf(trt[3]), W11=__expf(trt[4]), W12=__expf(trt[5]);
    float W20=__expf(trt[6]), W21=__expf(trt[7]), W22=__expf(trt[8]);

    const int t0 = tid * KPT;
    const float* ep = em  + ((size_t)b * S_ + t0) * 3;
    const int*   lp = lab + ((size_t)b * S_ + t0);

    // running chunk product: V (linear mantissas, row-major 3x3), S2 (log2 row scales)
    float V[9] = {1,0,0, 0,1,0, 0,0,1};
    float S2[3] = {0,0,0};

    float sc = 0.f;                       // gold-path score partial
    int prev = (tid > 0) ? lp[-1] : 0;    // label at t0-1
    float e0a=0.f, e0b=0.f, e0c=0.f;      // raw emissions at t==0 (thread 0 only)

    for (int it = 0; it < 8; ++it) {
        const float4 va = *(const float4*)(ep + it*12);
        const float4 vb = *(const float4*)(ep + it*12 + 4);
        const float4 vc = *(const float4*)(ep + it*12 + 8);
        const int4   lv = *(const int4*)(lp + it*4);

        auto step = [&](int t, int l, float ea, float eb, float ec){
            // ---- gold-path score ----
            float ee  = (l==1) ? eb : ((l==2) ? ec : ea);
            float trv = tLds[prev*3 + l];
            if (t == 0) { sc += sLds[l]; e0a=ea; e0b=eb; e0c=ec; }
            else        { sc += trv; }
            sc += ee;
            prev = l;
            // ---- semiring fold: V <- V ∘ (T + e_t), linear domain ----
            if (t > 0) {
                float E0=__expf(ea), E1=__expf(eb), E2=__expf(ec);
#pragma unroll
                for (int i=0;i<3;i++){
                    float a0=V[i*3+0], a1=V[i*3+1], a2=V[i*3+2];
                    V[i*3+0] = (a0*W00 + a1*W10 + a2*W20) * E0;
                    V[i*3+1] = (a0*W01 + a1*W11 + a2*W21) * E1;
                    V[i*3+2] = (a0*W02 + a1*W12 + a2*W22) * E2;
                }
            }
        };

        const int tb = t0 + it*4;
        step(tb+0, lv.x, va.x, va.y, va.z);
        step(tb+1, lv.y, va.w, vb.x, vb.y);
        step(tb+2, lv.z, vb.z, vb.w, vc.x);
        step(tb+3, lv.w, vc.y, vc.z, vc.w);

        // renorm every 4 steps (exact pow2 scaling; worst-case growth ~2^45 < 2^127)
        renorm3(V[0],V[1],V[2],S2[0]);
        renorm3(V[3],V[4],V[5],S2[1]);
        renorm3(V[6],V[7],V[8],S2[2]);
    }

    // end-transition contribution (last thread holds label at t = S-1)
    if (tid == TPB-1) sc += eLds[prev];

    // ---- wave-level tree combine (ordered: self=earlier ∘ shuffled=later) ----
#pragma unroll
    for (int off = 1; off < 64; off <<= 1) {
        float bv[9], bs[3];
#pragma unroll
        for (int k=0;k<9;k++) bv[k] = __shfl_down(V[k], (unsigned)off, 64);
#pragma unroll
        for (int k=0;k<3;k++) bs[k] = __shfl_down(S2[k], (unsigned)off, 64);
        combine9(V, S2, bv, bs);
    }
    // score: wave sum
#pragma unroll
    for (int off = 32; off; off >>= 1) sc += __shfl_down(sc, (unsigned)off, 64);

    if (ln == 0) {
#pragma unroll
        for (int k=0;k<9;k++) wV[wv][k] = V[k];
#pragma unroll
        for (int k=0;k<3;k++) wS2[wv][k] = S2[k];
        wSc[wv] = sc;
    }
    __syncthreads();

    if (tid == 0) {
        float A[9], As[3];
#pragma unroll
        for (int k=0;k<9;k++) A[k] = wV[0][k];
#pragma unroll
        for (int k=0;k<3;k++) As[k] = wS2[0][k];
#pragma unroll
        for (int w=1; w<4; ++w) combine9(A, As, wV[w], wS2[w]);

        // convert total product to log2 domain
        float P2[9];
#pragma unroll
        for (int i=0;i<3;i++)
#pragma unroll
            for (int j=0;j<3;j++)
                P2[i*3+j] = log2f_(fmaxf(A[i*3+j], 1e-37f)) + As[i];

        // alpha0 = start + e0 (log2 units), fold through product, then end transitions
        float a0 = (sLds[0] + e0a) * LOG2E;
        float a1 = (sLds[1] + e0b) * LOG2E;
        float a2 = (sLds[2] + e0c) * LOG2E;
        float q0 = lse3_2(a0+P2[0], a1+P2[3], a2+P2[6]);
        float q1 = lse3_2(a0+P2[1], a1+P2[4], a2+P2[7]);
        float q2 = lse3_2(a0+P2[2], a1+P2[5], a2+P2[8]);
        float lz2 = lse3_2(q0 + eLds[0]*LOG2E, q1 + eLds[1]*LOG2E, q2 + eLds[2]*LOG2E);
        float logz = lz2 * LN2;

        float scT = (wSc[0]+wSc[1]) + (wSc[2]+wSc[3]);
        ws[b] = logz - scT;   // per-batch contribution to NLL
    }
}

extern "C" __global__ __launch_bounds__(TPB)
void crf_sum(const float* __restrict__ ws, float* __restrict__ out)
{
    const int tid = threadIdx.x;           // 256 threads, 1024 values
    float4 v = ((const float4*)ws)[tid];
    float s = (v.x + v.y) + (v.z + v.w);
#pragma unroll
    for (int off = 32; off; off >>= 1) s += __shfl_down(s, (unsigned)off, 64);
    __shared__ float wsum[4];
    if ((tid & 63) == 0) wsum[tid >> 6] = s;
    __syncthreads();
    if (tid == 0) out[0] = (wsum[0]+wsum[1]) + (wsum[2]+wsum[3]);
}

extern "C" void kernel_launch(void* const* d_in, const int* in_sizes, int n_in,
                              void* d_out, int out_size, void* d_ws, size_t ws_size,
                              hipStream_t stream) {
    const float* em  = (const float*)d_in[0];
    const int*   lab = (const int*)d_in[1];
    const float* stt = (const float*)d_in[2];
    const float* trt = (const float*)d_in[3];
    const float* ent = (const float*)d_in[4];
    float* out = (float*)d_out;
    float* ws  = (float*)d_ws;   // 1024 floats of per-batch partials

    const int B = in_sizes[1] / S_;   // 1024
    crf_fwd<<<B, TPB, 0, stream>>>(em, lab, stt, trt, ent, ws);
    crf_sum<<<1, TPB, 0, stream>>>(ws, out);
}

// Round 4
// 192.721 us; speedup vs baseline: 1.0588x; 1.0588x over previous
//
#include <hip/hip_runtime.h>

#define LOG2E 1.44269504088896340736f
#define LN2   0.69314718055994530942f
#define S_    8192
#define TPB   512
#define KPT   16   // timesteps per thread: 512*16 = 8192
#define NWAVE (TPB/64)

#if __has_builtin(__builtin_amdgcn_exp2f)
__device__ __forceinline__ float exp2f_(float x){ return __builtin_amdgcn_exp2f(x); }
#else
__device__ __forceinline__ float exp2f_(float x){ return __expf(x * LN2); }
#endif
#if __has_builtin(__builtin_amdgcn_logf)
__device__ __forceinline__ float log2f_(float x){ return __builtin_amdgcn_logf(x); }
#else
__device__ __forceinline__ float log2f_(float x){ return __logf(x) * LOG2E; }
#endif

// log-sum-exp of 3 values in log2 domain
__device__ __forceinline__ float lse3_2(float a, float b, float c){
    float m = fmaxf(fmaxf(a,b),c);
    return m + log2f_(exp2f_(a-m) + exp2f_(b-m) + exp2f_(c-m));
}

// renorm row (a,b,c): scale max into [1,2) by an exact power of two; s += log2(scale removed)
__device__ __forceinline__ void renorm3(float&a, float&b, float&c, float&s){
    float m = fmaxf(fmaxf(a,b),c);
    int e = (__float_as_int(m) >> 23) & 0xff;      // biased exponent of max
    float rs = __int_as_float((254 - e) << 23);    // 2^(127-e), exact
    a *= rs; b *= rs; c *= rs;
    s += (float)(e - 127);
}

// (A,As) <- (A,As) ∘ (Bv,Bs): semiring product; rows = linear mantissa + log2 row-scale
__device__ __forceinline__ void combine9(float* A, float* As, const float* Bv, const float* Bs){
    float mb = fmaxf(fmaxf(Bs[0],Bs[1]),Bs[2]);
    float f0 = exp2f_(Bs[0]-mb), f1 = exp2f_(Bs[1]-mb), f2 = exp2f_(Bs[2]-mb);
    float b00=Bv[0]*f0, b01=Bv[1]*f0, b02=Bv[2]*f0;
    float b10=Bv[3]*f1, b11=Bv[4]*f1, b12=Bv[5]*f1;
    float b20=Bv[6]*f2, b21=Bv[7]*f2, b22=Bv[8]*f2;
#pragma unroll
    for (int i=0;i<3;i++){
        float a0=A[i*3+0], a1=A[i*3+1], a2=A[i*3+2];
        float c0 = a0*b00 + a1*b10 + a2*b20;
        float c1 = a0*b01 + a1*b11 + a2*b21;
        float c2 = a0*b02 + a1*b12 + a2*b22;
        float s  = As[i] + mb;
        renorm3(c0,c1,c2,s);
        A[i*3+0]=c0; A[i*3+1]=c1; A[i*3+2]=c2; As[i]=s;
    }
}

extern "C" __global__ __launch_bounds__(TPB)
void crf_fwd(const float* __restrict__ em, const int* __restrict__ lab,
             const float* __restrict__ stt, const float* __restrict__ trt,
             const float* __restrict__ ent, float* __restrict__ ws)
{
    const int b   = blockIdx.x;
    const int tid = threadIdx.x;
    const int ln  = tid & 63;
    const int wv  = tid >> 6;

    __shared__ float tLds[9], sLds[3], eLds[3];
    __shared__ float wV[NWAVE][9];
    __shared__ float wS2[NWAVE][3];
    __shared__ float wSc[NWAVE];
    if (tid < 9) tLds[tid] = trt[tid];
    if (tid < 3) { sLds[tid] = stt[tid]; eLds[tid] = ent[tid]; }
    __syncthreads();

    // W[k][j] = exp(T[k][j]) — linear-domain transition weights
    float W00=__expf(trt[0]), W01=__expf(trt[1]), W02=__expf(trt[2]);
    float W10=__expf(trt[3]), W11=__expf(trt[4]), W12=__expf(trt[5]);
    float W20=__expf(trt[6]), W21=__expf(trt[7]), W22=__expf(trt[8]);

    const int t0 = tid * KPT;
    const float* ep = em  + ((size_t)b * S_ + t0) * 3;
    const int*   lp = lab + ((size_t)b * S_ + t0);

    // running chunk product: V (linear mantissas, row-major 3x3), S2 (log2 row scales)
    float V[9] = {1,0,0, 0,1,0, 0,0,1};
    float S2[3] = {0,0,0};

    float sc = 0.f;                       // gold-path score partial
    int prev = (tid > 0) ? lp[-1] : 0;    // label at t0-1
    float e0a=0.f, e0b=0.f, e0c=0.f;      // raw emissions at t==0 (thread 0 only)

    for (int it = 0; it < KPT/4; ++it) {
        const float4 va = *(const float4*)(ep + it*12);
        const float4 vb = *(const float4*)(ep + it*12 + 4);
        const float4 vc = *(const float4*)(ep + it*12 + 8);
        const int4   lv = *(const int4*)(lp + it*4);

        auto step = [&](int t, int l, float ea, float eb, float ec){
            // ---- gold-path score ----
            float ee  = (l==1) ? eb : ((l==2) ? ec : ea);
            float trv = tLds[prev*3 + l];
            if (t == 0) { sc += sLds[l]; e0a=ea; e0b=eb; e0c=ec; }
            else        { sc += trv; }
            sc += ee;
            prev = l;
            // ---- semiring fold: V <- V ∘ (T + e_t), linear domain ----
            if (t > 0) {
                float E0=__expf(ea), E1=__expf(eb), E2=__expf(ec);
#pragma unroll
                for (int i=0;i<3;i++){
                    float a0=V[i*3+0], a1=V[i*3+1], a2=V[i*3+2];
                    V[i*3+0] = (a0*W00 + a1*W10 + a2*W20) * E0;
                    V[i*3+1] = (a0*W01 + a1*W11 + a2*W21) * E1;
                    V[i*3+2] = (a0*W02 + a1*W12 + a2*W22) * E2;
                }
            }
        };

        const int tb = t0 + it*4;
        step(tb+0, lv.x, va.x, va.y, va.z);
        step(tb+1, lv.y, va.w, vb.x, vb.y);
        step(tb+2, lv.z, vb.z, vb.w, vc.x);
        step(tb+3, lv.w, vc.y, vc.z, vc.w);

        // renorm every 4 steps (exact pow2 scaling; worst-case growth ~2^45 < 2^127)
        renorm3(V[0],V[1],V[2],S2[0]);
        renorm3(V[3],V[4],V[5],S2[1]);
        renorm3(V[6],V[7],V[8],S2[2]);
    }

    // end-transition contribution (last thread holds label at t = S-1)
    if (tid == TPB-1) sc += eLds[prev];

    // ---- wave-level tree combine (ordered: self=earlier ∘ shuffled=later) ----
#pragma unroll
    for (int off = 1; off < 64; off <<= 1) {
        float bv[9], bs[3];
#pragma unroll
        for (int k=0;k<9;k++) bv[k] = __shfl_down(V[k], (unsigned)off, 64);
#pragma unroll
        for (int k=0;k<3;k++) bs[k] = __shfl_down(S2[k], (unsigned)off, 64);
        combine9(V, S2, bv, bs);
    }
    // score: wave sum
#pragma unroll
    for (int off = 32; off; off >>= 1) sc += __shfl_down(sc, (unsigned)off, 64);

    if (ln == 0) {
#pragma unroll
        for (int k=0;k<9;k++) wV[wv][k] = V[k];
#pragma unroll
        for (int k=0;k<3;k++) wS2[wv][k] = S2[k];
        wSc[wv] = sc;
    }
    __syncthreads();

    if (tid == 0) {
        float A[9], As[3];
#pragma unroll
        for (int k=0;k<9;k++) A[k] = wV[0][k];
#pragma unroll
        for (int k=0;k<3;k++) As[k] = wS2[0][k];
#pragma unroll
        for (int w=1; w<NWAVE; ++w) combine9(A, As, wV[w], wS2[w]);

        // convert total product to log2 domain
        float P2[9];
#pragma unroll
        for (int i=0;i<3;i++)
#pragma unroll
            for (int j=0;j<3;j++)
                P2[i*3+j] = log2f_(fmaxf(A[i*3+j], 1e-37f)) + As[i];

        // alpha0 = start + e0 (log2 units), fold through product, then end transitions
        float a0 = (sLds[0] + e0a) * LOG2E;
        float a1 = (sLds[1] + e0b) * LOG2E;
        float a2 = (sLds[2] + e0c) * LOG2E;
        float q0 = lse3_2(a0+P2[0], a1+P2[3], a2+P2[6]);
        float q1 = lse3_2(a0+P2[1], a1+P2[4], a2+P2[7]);
        float q2 = lse3_2(a0+P2[2], a1+P2[5], a2+P2[8]);
        float lz2 = lse3_2(q0 + eLds[0]*LOG2E, q1 + eLds[1]*LOG2E, q2 + eLds[2]*LOG2E);
        float logz = lz2 * LN2;

        float scT = 0.f;
#pragma unroll
        for (int w=0; w<NWAVE; ++w) scT += wSc[w];
        ws[b] = logz - scT;   // per-batch contribution to NLL
    }
}

extern "C" __global__ __launch_bounds__(256)
void crf_sum(const float* __restrict__ ws, float* __restrict__ out)
{
    const int tid = threadIdx.x;           // 256 threads, 1024 values
    float4 v = ((const float4*)ws)[tid];
    float s = (v.x + v.y) + (v.z + v.w);
#pragma unroll
    for (int off = 32; off; off >>= 1) s += __shfl_down(s, (unsigned)off, 64);
    __shared__ float wsum[4];
    if ((tid & 63) == 0) wsum[tid >> 6] = s;
    __syncthreads();
    if (tid == 0) out[0] = (wsum[0]+wsum[1]) + (wsum[2]+wsum[3]);
}

extern "C" void kernel_launch(void* const* d_in, const int* in_sizes, int n_in,
                              void* d_out, int out_size, void* d_ws, size_t ws_size,
                              hipStream_t stream) {
    const float* em  = (const float*)d_in[0];
    const int*   lab = (const int*)d_in[1];
    const float* stt = (const float*)d_in[2];
    const float* trt = (const float*)d_in[3];
    const float* ent = (const float*)d_in[4];
    float* out = (float*)d_out;
    float* ws  = (float*)d_ws;   // 1024 floats of per-batch partials

    const int B = in_sizes[1] / S_;   // 1024
    crf_fwd<<<B, TPB, 0, stream>>>(em, lab, stt, trt, ent, ws);
    crf_sum<<<1, 256, 0, stream>>>(ws, out);
}

// Round 5
// 187.412 us; speedup vs baseline: 1.0888x; 1.0283x over previous
//
#include <hip/hip_runtime.h>

#define LOG2E 1.44269504088896340736f
#define LN2   0.69314718055994530942f
#define S_    8192
#define HALF  4096
#define TPB   512
#define KPT   8      // 512 threads * 8 steps = 4096 steps per block (half sequence)
#define NWAVE 8

#if __has_builtin(__builtin_amdgcn_exp2f)
__device__ __forceinline__ float exp2f_(float x){ return __builtin_amdgcn_exp2f(x); }
#else
__device__ __forceinline__ float exp2f_(float x){ return __expf(x * LN2); }
#endif
#if __has_builtin(__builtin_amdgcn_logf)
__device__ __forceinline__ float log2f_(float x){ return __builtin_amdgcn_logf(x); }
#else
__device__ __forceinline__ float log2f_(float x){ return __logf(x) * LOG2E; }
#endif

// renorm 9-entry nonneg matrix: scale max into [1,2) by exact pow2; s += log2 removed
__device__ __forceinline__ void renorm9(float* V, float& s){
    float m = fmaxf(fmaxf(fmaxf(V[0],V[1]),fmaxf(V[2],V[3])),
                    fmaxf(fmaxf(V[4],V[5]),fmaxf(V[6],V[7])));
    m = fmaxf(m, V[8]);
    int e = (__float_as_int(m) >> 23) & 0xff;
    float rs = __int_as_float((254 - e) << 23);   // 2^(127-e), exact
#pragma unroll
    for (int k=0;k<9;++k) V[k] *= rs;
    s += (float)(e - 127);
}

__device__ __forceinline__ void mul33(float* C, const float* A, const float* B){
#pragma unroll
    for (int i=0;i<3;i++){
        float a0=A[i*3], a1=A[i*3+1], a2=A[i*3+2];
#pragma unroll
        for (int j=0;j<3;j++)
            C[i*3+j] = a0*B[j] + a1*B[3+j] + a2*B[6+j];
    }
}

// Block = half sequence: blockIdx = 2*b + h, steps [h*4096, (h+1)*4096).
// Coalesced load -> reg -> transposed LDS (513-slot rows, conflict-free b128)
// -> per-thread 8-step semiring fold -> wave shfl tree -> cross-wave serial
// -> 16-float record in ws: V[9], S2, score, e0[3] (e0 valid for h==0).
extern "C" __global__ __launch_bounds__(TPB, 4)
void crf_fwd(const float* __restrict__ em, const int* __restrict__ lab,
             const float* __restrict__ stt, const float* __restrict__ trt,
             const float* __restrict__ ent, float* __restrict__ ws)
{
    const int bid = blockIdx.x;
    const int b = bid >> 1, h = bid & 1;
    const int tid = threadIdx.x;
    const int ln = tid & 63, wv = tid >> 6;

    __shared__ float4 emS[6*513];    // 49.2 KB: slot (j,T) at j*513+T, thread T owns j=0..5
    __shared__ int4   labS[2*513];   // 16.4 KB
    __shared__ float  wM[NWAVE][10];
    __shared__ float  wSc[NWAVE];
    __shared__ float  tT[9], tS[3];

    const float4* emG = (const float4*)(em + ((size_t)b*S_ + (size_t)h*HALF)*3);
    const int4*   lbG = (const int4*)(lab + ((size_t)b*S_ + (size_t)h*HALF));

    // ---- coalesced global -> regs (lane-contiguous float4/int4) ----
    float4 er0=emG[tid],      er1=emG[512+tid],  er2=emG[1024+tid],
           er3=emG[1536+tid], er4=emG[2048+tid], er5=emG[2560+tid];
    int4   lr0=lbG[tid],      lr1=lbG[512+tid];
    int prevg = 0;
    if (tid==0 && h==1) prevg = ((const int*)lbG)[-1];  // label at 4095

    if (tid < 9) tT[tid] = trt[tid];
    if (tid < 3) tS[tid] = stt[tid];

    // linear-domain transition weights (overlaps load latency)
    float W00=__expf(trt[0]), W01=__expf(trt[1]), W02=__expf(trt[2]);
    float W10=__expf(trt[3]), W11=__expf(trt[4]), W12=__expf(trt[5]);
    float W20=__expf(trt[6]), W21=__expf(trt[7]), W22=__expf(trt[8]);

    // ---- transpose-scatter into LDS ----
    // global slot sg = k*512+tid holds 16B of em; owner thread T=sg/6, sub j=sg%6
    {
        #define EMW(k, reg) { int sg=(k)*512+tid; int T=sg/6; int j=sg-T*6; emS[j*513+T]=reg; }
        EMW(0,er0) EMW(1,er1) EMW(2,er2) EMW(3,er3) EMW(4,er4) EMW(5,er5)
        #undef EMW
        { int sg = tid;       labS[(sg&1)*513 + (sg>>1)] = lr0; }
        { int sg = 512 + tid; labS[(sg&1)*513 + (sg>>1)] = lr1; }
    }
    __syncthreads();

    // ---- gather own chunk: 6x b128 em + 2x b128 lab, conflict-free ----
    const int t = tid;
    float ew[24];
    *(float4*)&ew[0]  = emS[t];        *(float4*)&ew[4]  = emS[513+t];
    *(float4*)&ew[8]  = emS[2*513+t];  *(float4*)&ew[12] = emS[3*513+t];
    *(float4*)&ew[16] = emS[4*513+t];  *(float4*)&ew[20] = emS[5*513+t];
    int lw[8];
    *(int4*)&lw[0] = labS[t];  *(int4*)&lw[4] = labS[513+t];

    int prev;
    if (t > 0) prev = ((const int*)labS)[(513 + (t-1))*4 + 3]; // label at t*8-1
    else       prev = prevg;   // h==1: global; h==0: unused

    // ---- semiring fold: V <- V * (W .* E_t), single pow2 scale ----
    float V[9] = {1,0,0, 0,1,0, 0,0,1};
    float S2 = 0.f, sc = 0.f;
    const bool head = (h==0 && t==0);
#pragma unroll
    for (int s=0; s<KPT; ++s){
        float ea=ew[3*s], eb=ew[3*s+1], ec=ew[3*s+2];
        int l = lw[s];
        float ee = (l==1) ? eb : ((l==2) ? ec : ea);
        if (s==0 && head) sc += tS[l] + ee;      // start transition + e0
        else              sc += tT[prev*3+l] + ee;
        prev = l;
        if (!(s==0 && head)) {                    // step 0 of sequence is alpha0, not a factor
            float E0=__expf(ea), E1=__expf(eb), E2=__expf(ec);
#pragma unroll
            for (int i=0;i<3;i++){
                float a0=V[i*3], a1=V[i*3+1], a2=V[i*3+2];
                V[i*3]  =(a0*W00+a1*W10+a2*W20)*E0;
                V[i*3+1]=(a0*W01+a1*W11+a2*W21)*E1;
                V[i*3+2]=(a0*W02+a1*W12+a2*W22)*E2;
            }
        }
        if (s==3 || s==7) renorm9(V, S2);   // growth <= ~2^42 per 4 steps
    }

    // ---- ordered wave tree: lane i := chunk_i ∘ chunk_{i+off} ----
#pragma unroll
    for (int off=1; off<64; off<<=1){
        float bv[9];
#pragma unroll
        for (int k=0;k<9;++k) bv[k] = __shfl_down(V[k], (unsigned)off, 64);
        float bs2 = __shfl_down(S2, (unsigned)off, 64);
        float C[9]; mul33(C, V, bv);
        S2 += bs2;
        renorm9(C, S2);
#pragma unroll
        for (int k=0;k<9;++k) V[k]=C[k];
    }
#pragma unroll
    for (int off=32; off; off>>=1) sc += __shfl_down(sc, (unsigned)off, 64);

    if (ln==0){
#pragma unroll
        for (int k=0;k<9;++k) wM[wv][k]=V[k];
        wM[wv][9]=S2; wSc[wv]=sc;
    }
    __syncthreads();

    if (tid==0){
        float A[9], As = wM[0][9], scT = wSc[0];
#pragma unroll
        for (int k=0;k<9;++k) A[k]=wM[0][k];
#pragma unroll
        for (int w=1; w<NWAVE; ++w){
            float C[9]; mul33(C, A, wM[w]);
            As += wM[w][9];
            renorm9(C, As);
#pragma unroll
            for (int k=0;k<9;++k) A[k]=C[k];
            scT += wSc[w];
        }
        float* r = ws + (size_t)bid*16;
#pragma unroll
        for (int k=0;k<9;++k) r[k]=A[k];
        r[9]=As; r[10]=scT;
        float4 e0 = emS[0];         // first step's emissions of this half
        r[11]=e0.x; r[12]=e0.y; r[13]=e0.z;
    }
}

// chain the two half-products, fold alpha0 + end transitions, sum NLL
extern "C" __global__ __launch_bounds__(1024)
void crf_fin(const float* __restrict__ ws, const float* __restrict__ stt,
             const float* __restrict__ ent, float* __restrict__ out, int B)
{
    const int b = threadIdx.x;
    float nll = 0.f;
    if (b < B){
        const float* r0 = ws + (size_t)(2*b)*16;
        const float* r1 = ws + (size_t)(2*b+1)*16;
        float C[9];
#pragma unroll
        for (int i=0;i<3;i++){
            float a0=r0[i*3], a1=r0[i*3+1], a2=r0[i*3+2];
#pragma unroll
            for (int j=0;j<3;j++)
                C[i*3+j] = a0*r1[j] + a1*r1[3+j] + a2*r1[6+j];
        }
        float S  = r0[9] + r1[9];
        float sc = r0[10] + r1[10];
        float a0=(stt[0]+r0[11])*LOG2E, a1=(stt[1]+r0[12])*LOG2E, a2=(stt[2]+r0[13])*LOG2E;
        float am = fmaxf(fmaxf(a0,a1),a2);
        float w0=exp2f_(a0-am), w1=exp2f_(a1-am), w2=exp2f_(a2-am);
        float q0=w0*C[0]+w1*C[3]+w2*C[6];
        float q1=w0*C[1]+w1*C[4]+w2*C[7];
        float q2=w0*C[2]+w1*C[5]+w2*C[8];
        float z = q0*exp2f_(ent[0]*LOG2E) + q1*exp2f_(ent[1]*LOG2E) + q2*exp2f_(ent[2]*LOG2E);
        float logz = (am + S + log2f_(z)) * LN2;
        nll = logz - sc;
    }
#pragma unroll
    for (int off=32; off; off>>=1) nll += __shfl_down(nll, (unsigned)off, 64);
    __shared__ float acc[16];
    if ((threadIdx.x & 63)==0) acc[threadIdx.x>>6] = nll;
    __syncthreads();
    if (threadIdx.x==0){
        float s=0.f;
#pragma unroll
        for (int k=0;k<16;++k) s += acc[k];
        out[0] = s;
    }
}

extern "C" void kernel_launch(void* const* d_in, const int* in_sizes, int n_in,
                              void* d_out, int out_size, void* d_ws, size_t ws_size,
                              hipStream_t stream) {
    const float* em  = (const float*)d_in[0];
    const int*   lab = (const int*)d_in[1];
    const float* stt = (const float*)d_in[2];
    const float* trt = (const float*)d_in[3];
    const float* ent = (const float*)d_in[4];
    float* out = (float*)d_out;
    float* ws  = (float*)d_ws;     // needs 2*B*16 floats = 131 KB for B=1024

    const int B = in_sizes[1] / S_;
    crf_fwd<<<2*B, TPB, 0, stream>>>(em, lab, stt, trt, ent, ws);
    crf_fin<<<1, 1024, 0, stream>>>(ws, stt, ent, out, B);
}